// Round 5
// baseline (90.720 us; speedup 1.0000x reference)
//
#include <hip/hip_runtime.h>

typedef __attribute__((ext_vector_type(4))) float f32x4;
typedef __attribute__((ext_vector_type(8))) short short8;
typedef __attribute__((ext_vector_type(4))) unsigned int u32x4;

#define N_ROWS 4096
#define KDIM   4096
#define NC     96     // [cls 0..19][r1 20..40][r2 41..61][pad][det 64..83][pad]
#define GSPLIT 16     // k splits (256 k each)

__device__ inline short f2bf(float f) {
  unsigned u = __builtin_bit_cast(unsigned, f);
  u += 0x7FFFu + ((u >> 16) & 1u);   // RNE
  return (short)(u >> 16);
}

__device__ inline unsigned cvtpk(float lo, float hi) {
  unsigned r;
  asm("v_cvt_pk_bf16_f32 %0, %1, %2" : "=v"(r) : "v"(lo), "v"(hi));
  return r;
}

// ---------------- K0: pack weights into bf16 B-fragment order (R0-verified mapping) ----------------
// Wp flat index: ((K*6 + ct)*64 + l)*8 + j ; k = K*32 + (l>>4)*8 + j ; col = ct*16 + (l&15)
__global__ void k_pack(const float* __restrict__ Wcls, const float* __restrict__ Wr1,
                       const float* __restrict__ Wr2, const float* __restrict__ Wdet,
                       ushort* __restrict__ Wp) {
  int t = blockIdx.x * 256 + threadIdx.x;            // 0 .. 128*3072-1
  int K = t / 3072;
  int rem = t - K * 3072;
  int ct = rem >> 9;
  int rem2 = rem & 511;
  int l = rem2 >> 3;
  int j = rem2 & 7;
  int k = K * 32 + (l >> 4) * 8 + j;
  int col = ct * 16 + (l & 15);
  float v = 0.f;
  if (col < 20)                 v = Wcls[k * 20 + col];
  else if (col < 41)            v = Wr1[k * 21 + (col - 20)];
  else if (col < 62)            v = Wr2[k * 21 + (col - 41)];
  else if (col >= 64 && col < 84) v = Wdet[k * 20 + (col - 64)];
  Wp[t] = (ushort)f2bf(v);
}

// ---------------- K1: bf16 MFMA GEMM — B in LDS (1 barrier), barrier-free k-loop, D=2 reg pipeline ----------------
#define GLo(dst, base, OFF) \
  asm volatile("global_load_dwordx4 %0, %1, off offset:%c2" : "=v"(dst) : "v"(base), "i"(OFF) : "memory")
#define WAITV(N) asm volatile("s_waitcnt vmcnt(" #N ")" ::: "memory")
#define SB() __builtin_amdgcn_sched_barrier(0)

// issue the 6 A-loads (roi lo/hi, frame lo/hi, ctx lo/hi) for kstep KS into raw[BF]
#define ISSUEA(KS, BF) do {                              \
    GLo(raw[BF][0], pr, (KS)*128);                       \
    GLo(raw[BF][1], pr, (KS)*128 + 16);                  \
    GLo(raw[BF][2], pf, (KS)*128);                       \
    GLo(raw[BF][3], pf, (KS)*128 + 16);                  \
    GLo(raw[BF][4], pc, (KS)*128);                       \
    GLo(raw[BF][5], pc, (KS)*128 + 16);                  \
  } while (0)

__global__ __launch_bounds__(256, 3) void k_gemm(const float* __restrict__ roi,
    const float* __restrict__ frame, const float* __restrict__ ctx,
    const ushort* __restrict__ Wp, float* __restrict__ Spart) {
  const int t    = threadIdx.x;
  const int lane = t & 63;
  const int wid  = t >> 6;            // wave 0..3 -> independent 16-row tile
  const int rb   = blockIdx.x >> 4;   // 64-row block (0..63)
  const int g    = blockIdx.x & 15;   // k split (256 floats)

  __shared__ alignas(16) ushort smemB[8 * 6 * 64 * 8];   // 48KB: B frags for 8 ksteps

  // ---- stage B slice (8 ksteps x 6144B, contiguous in Wp) into LDS ----
  {
    const ushort* src = Wp + (size_t)g * 24576;   // 8*3072 ushorts
    for (int r = 0; r < 12; ++r) {
      const int e = r * 256 + t;                  // 0..3071 chunks of 16B
      *(short8*)(&smemB[e * 8]) = *(const short8*)(src + e * 8);
    }
  }
  __syncthreads();   // drains all counters; asm vmcnt bookkeeping starts clean

  const int row = rb * 64 + wid * 16 + (lane & 15);
  const size_t aoff = (size_t)row * KDIM + g * 256 + (lane >> 4) * 8;
  const float* pr = roi   + aoff;
  const float* pf = frame + aoff;
  const float* pc = ctx   + aoff;

  f32x4 raw[3][6];
  f32x4 acc[6];
#pragma unroll
  for (int i = 0; i < 6; ++i) acc[i] = (f32x4){0.f, 0.f, 0.f, 0.f};

  ISSUEA(0, 0);
  ISSUEA(1, 1);

#pragma unroll
  for (int ks = 0; ks < 8; ++ks) {
    if (ks < 6) ISSUEA(ks + 2, (ks + 2) % 3);
    if (ks < 6)      { WAITV(12); }
    else if (ks == 6){ WAITV(6); }
    else             { WAITV(0); }
    SB();
    const f32x4* c = raw[ks % 3];
    u32x4 uR, uD;
    uR.x = cvtpk(c[0][0], c[0][1]); uR.y = cvtpk(c[0][2], c[0][3]);
    uR.z = cvtpk(c[1][0], c[1][1]); uR.w = cvtpk(c[1][2], c[1][3]);
    uD.x = cvtpk(c[2][0] - c[4][0], c[2][1] - c[4][1]);
    uD.y = cvtpk(c[2][2] - c[4][2], c[2][3] - c[4][3]);
    uD.z = cvtpk(c[3][0] - c[5][0], c[3][1] - c[5][1]);
    uD.w = cvtpk(c[3][2] - c[5][2], c[3][3] - c[5][3]);
    const short8 aR = __builtin_bit_cast(short8, uR);
    const short8 aD = __builtin_bit_cast(short8, uD);
#pragma unroll
    for (int ct = 0; ct < 6; ++ct) {
      const short8 b = *(const short8*)(&smemB[((ks * 6 + ct) * 64 + lane) * 8]);
      acc[ct] = __builtin_amdgcn_mfma_f32_16x16x32_bf16(ct < 4 ? aR : aD, b, acc[ct], 0, 0, 0);
    }
  }

  // epilogue: direct Spart store (waves own disjoint 16-row tiles)
  float* out = Spart + (size_t)g * (N_ROWS * NC) + (size_t)(rb * 64 + wid * 16) * NC;
  const int rbase = (lane >> 4) * 4;   // C/D: col=lane&15, row=(lane>>4)*4+reg [m89-verified]
  const int col = lane & 15;
#pragma unroll
  for (int ct = 0; ct < 6; ++ct)
#pragma unroll
    for (int r = 0; r < 4; ++r)
      out[(size_t)(rbase + r) * NC + ct * 16 + col] = acc[ct][r];
}

// ---------------- K2: fused split-K reduce + per-row softmaxes ----------------
__global__ void k_rr(const float* __restrict__ Spart, const float* __restrict__ bcls,
    const float* __restrict__ br1, const float* __restrict__ br2,
    float* __restrict__ S, float* __restrict__ clsp, float* __restrict__ rp1,
    float* __restrict__ lse1, float* __restrict__ lse2) {
  const int b = blockIdx.x;            // 128 blocks x 32 rows
  const int t = threadIdx.x;
  const int base = b * 3072;
#pragma unroll
  for (int j = 0; j < 12; ++j) {
    const int e = base + j * 256 + t;
    float s = 0.f;
#pragma unroll
    for (int gg = 0; gg < GSPLIT; ++gg) s += Spart[(size_t)gg * (N_ROWS * NC) + e];
    S[e] = s;
  }
  __syncthreads();
  if (t < 32) {
    const int i = b * 32 + t;
    const float* sr = S + (size_t)i * NC;
    float s[21];
    float m = -3.4e38f;
    for (int c = 0; c < 20; ++c) { s[c] = sr[c] + bcls[c]; m = fmaxf(m, s[c]); }
    float sum = 0.f;
    for (int c = 0; c < 20; ++c) { float e = expf(s[c] - m); s[c] = e; sum += e; }
    float inv = 1.f / sum;
    for (int c = 0; c < 20; ++c) clsp[(size_t)i * 20 + c] = s[c] * inv;
    m = -3.4e38f;
    for (int c = 0; c < 21; ++c) { s[c] = sr[20 + c] + br1[c]; m = fmaxf(m, s[c]); }
    sum = 0.f;
    for (int c = 0; c < 21; ++c) { float e = expf(s[c] - m); s[c] = e; sum += e; }
    lse1[i] = m + logf(sum);
    inv = 1.f / sum;
    for (int c = 0; c < 21; ++c) rp1[(size_t)i * 21 + c] = s[c] * inv;
    m = -3.4e38f;
    for (int c = 0; c < 21; ++c) { s[c] = sr[41 + c] + br2[c]; m = fmaxf(m, s[c]); }
    sum = 0.f;
    for (int c = 0; c < 21; ++c) sum += expf(s[c] - m);
    lse2[i] = m + logf(sum);
  }
}

// ---------------- K3: per-column (det softmax stats, det_cls_score, argmaxes -> seed boxes) ----------------
__global__ __launch_bounds__(256) void k_col(const float* __restrict__ S,
    const float* __restrict__ clsp, const float* __restrict__ rp1,
    const float* __restrict__ isw, const float* __restrict__ ssb,
    const float* __restrict__ bcls,
    float* __restrict__ dcs, float* __restrict__ b1out, float* __restrict__ b2out) {
  const int c = blockIdx.x;
  const int t = threadIdx.x;
  __shared__ float rv[256];
  __shared__ int ri[256];
  float m = -3.4e38f;
  for (int i = t; i < N_ROWS; i += 256) m = fmaxf(m, S[(size_t)i * NC + 64 + c]);
  rv[t] = m; __syncthreads();
  for (int o = 128; o; o >>= 1) { if (t < o) rv[t] = fmaxf(rv[t], rv[t + o]); __syncthreads(); }
  const float M = rv[0]; __syncthreads();
  float se = 0.f, scd = 0.f, v1b = -3.4e38f, v2b = -3.4e38f;
  int i1 = 0, i2 = 0;
  for (int i = t; i < N_ROWS; i += 256) {
    float w = isw[i];
    float e = expf(S[(size_t)i * NC + 64 + c] - M);
    se += e;
    scd += (S[(size_t)i * NC + c] + bcls[c]) * e;
    float v1 = clsp[(size_t)i * 20 + c] * e * w;
    if (v1 > v1b) { v1b = v1; i1 = i; }
    float v2 = rp1[(size_t)i * 21 + c + 1] * w;
    if (v2 > v2b) { v2b = v2; i2 = i; }
  }
  rv[t] = se; __syncthreads();
  for (int o = 128; o; o >>= 1) { if (t < o) rv[t] += rv[t + o]; __syncthreads(); }
  const float SE = rv[0]; __syncthreads();
  rv[t] = scd; __syncthreads();
  for (int o = 128; o; o >>= 1) { if (t < o) rv[t] += rv[t + o]; __syncthreads(); }
  const float SCD = rv[0]; __syncthreads();
  rv[t] = v1b; ri[t] = i1; __syncthreads();
  for (int o = 128; o; o >>= 1) {
    if (t < o) { if (rv[t + o] > rv[t] || (rv[t + o] == rv[t] && ri[t + o] < ri[t])) { rv[t] = rv[t + o]; ri[t] = ri[t + o]; } }
    __syncthreads();
  }
  const int I1 = ri[0]; __syncthreads();
  rv[t] = v2b; ri[t] = i2; __syncthreads();
  for (int o = 128; o; o >>= 1) {
    if (t < o) { if (rv[t + o] > rv[t] || (rv[t + o] == rv[t] && ri[t + o] < ri[t])) { rv[t] = rv[t + o]; ri[t] = ri[t + o]; } }
    __syncthreads();
  }
  const int I2 = ri[0];
  if (t == 0) {
    dcs[c] = SCD / SE;
    for (int q = 0; q < 4; ++q) {
      b1out[c * 4 + q] = ssb[(size_t)I1 * 5 + 1 + q];
      b2out[c * 4 + q] = ssb[(size_t)I2 * 5 + 1 + q];
    }
  }
}

// ---------------- K4: per-row IoU supervision + refine-loss partials ----------------
__global__ __launch_bounds__(256) void k_sup(const float* __restrict__ S,
    const float* __restrict__ ssb, const float* __restrict__ isw,
    const int* __restrict__ label,
    const float* __restrict__ b1in, const float* __restrict__ b2in,
    const float* __restrict__ lse1, const float* __restrict__ lse2,
    const float* __restrict__ br1, const float* __restrict__ br2,
    float* __restrict__ scal) {
  __shared__ float q1[20][4], q2[20][4], a1[20], a2[20];
  __shared__ int pos[20];
  const int t = threadIdx.x;
  if (t < 20) {
    for (int q = 0; q < 4; ++q) { q1[t][q] = b1in[t * 4 + q]; q2[t][q] = b2in[t * 4 + q]; }
    a1[t] = (q1[t][2] - q1[t][0] + 1.f) * (q1[t][3] - q1[t][1] + 1.f);
    a2[t] = (q2[t][2] - q2[t][0] + 1.f) * (q2[t][3] - q2[t][1] + 1.f);
    pos[t] = (label[t] == 1);
  }
  __syncthreads();
  const int i = blockIdx.x * 256 + t;
  const float bx1 = ssb[(size_t)i * 5 + 1], by1 = ssb[(size_t)i * 5 + 2];
  const float bx2 = ssb[(size_t)i * 5 + 3], by2 = ssb[(size_t)i * 5 + 4];
  const float ab = (bx2 - bx1 + 1.f) * (by2 - by1 + 1.f);
  const float w = isw[i];
  float p1 = 0.f, n1 = 0.f, p2 = 0.f, n2 = 0.f;
  {
    float mo = -2.f; int gt = 0;
    for (int c = 0; c < 20; ++c) {
      float v = -1.f;
      if (pos[c]) {
        float xx1 = fmaxf(bx1, q1[c][0]), yy1 = fmaxf(by1, q1[c][1]);
        float xx2 = fminf(bx2, q1[c][2]), yy2 = fminf(by2, q1[c][3]);
        float iw = fmaxf(xx2 - xx1 + 1.f, 0.f), ih = fmaxf(yy2 - yy1 + 1.f, 0.f);
        float inter = iw * ih;
        v = inter / (ab + a1[c] - inter);
      }
      if (v > mo) { mo = v; gt = c; }
    }
    bool fg = mo > 0.5f;
    bool bg = (mo >= 0.1f) && (mo < 0.5f);
    if (fg || bg) {
      int col = fg ? gt + 1 : 0;
      float lp = S[(size_t)i * NC + 20 + col] + br1[col] - lse1[i];
      p1 = w * lp; n1 = 1.f;
    }
  }
  {
    float mo = -2.f; int gt = 0;
    for (int c = 0; c < 20; ++c) {
      float v = -1.f;
      if (pos[c]) {
        float xx1 = fmaxf(bx1, q2[c][0]), yy1 = fmaxf(by1, q2[c][1]);
        float xx2 = fminf(bx2, q2[c][2]), yy2 = fminf(by2, q2[c][3]);
        float iw = fmaxf(xx2 - xx1 + 1.f, 0.f), ih = fmaxf(yy2 - yy1 + 1.f, 0.f);
        float inter = iw * ih;
        v = inter / (ab + a2[c] - inter);
      }
      if (v > mo) { mo = v; gt = c; }
    }
    bool fg = mo > 0.5f;
    bool bg = (mo >= 0.1f) && (mo < 0.5f);
    if (fg || bg) {
      int col = fg ? gt + 1 : 0;
      float lp = S[(size_t)i * NC + 41 + col] + br2[col] - lse2[i];
      p2 = w * lp; n2 = 1.f;
    }
  }
  __shared__ float rs[256];
  float sums[4] = {p1, n1, p2, n2};
  float tot[4];
  for (int q = 0; q < 4; ++q) {
    rs[t] = sums[q]; __syncthreads();
    for (int o = 128; o; o >>= 1) { if (t < o) rs[t] += rs[t + o]; __syncthreads(); }
    tot[q] = rs[0]; __syncthreads();
  }
  if (t == 0) {
    atomicAdd(&scal[0], tot[0]); atomicAdd(&scal[1], tot[1]);
    atomicAdd(&scal[2], tot[2]); atomicAdd(&scal[3], tot[3]);
  }
}

// ---------------- K5: final scalar ----------------
__global__ void k_final(const float* __restrict__ dcs, const int* __restrict__ label,
                        const float* __restrict__ scal, float* __restrict__ out) {
  if (threadIdx.x == 0 && blockIdx.x == 0) {
    float cd = 0.f;
    for (int c = 0; c < 20; ++c) {
      float lab = (float)label[c];
      cd += fmaxf(1.f - lab * dcs[c], 0.f);
    }
    cd *= (1.f / 20.f);
    float rl1 = -scal[0] / scal[1];
    float rl2 = -scal[2] / scal[3];
    out[0] = cd + 0.1f * (rl1 + rl2);
  }
}

// ---------------- workspace layout (all 16B aligned) ----------------
constexpr size_t OFF_S     = 0;                               // 4096*96*4 = 1572864
constexpr size_t OFF_SCAL  = OFF_S + (size_t)N_ROWS * NC * 4; // 16
constexpr size_t OFF_DCS   = OFF_SCAL + 16;                   // 80
constexpr size_t OFF_B1    = OFF_DCS + 80;                    // 320
constexpr size_t OFF_B2    = OFF_B1 + 320;                    // 320
constexpr size_t OFF_LSE1  = OFF_B2 + 320;                    // 16384
constexpr size_t OFF_LSE2  = OFF_LSE1 + 16384;                // 16384
constexpr size_t OFF_CLSP  = OFF_LSE2 + 16384;                // 327680
constexpr size_t OFF_RP1   = OFF_CLSP + 327680;               // 344064
constexpr size_t OFF_WP    = OFF_RP1 + 344064;                // 786432
constexpr size_t OFF_SPART = OFF_WP + 786432;                 // 16*4096*96*4 = 25165824

extern "C" void kernel_launch(void* const* d_in, const int* in_sizes, int n_in,
                              void* d_out, int out_size, void* d_ws, size_t ws_size,
                              hipStream_t stream) {
  const float* roi   = (const float*)d_in[0];
  const float* ctx   = (const float*)d_in[1];
  const float* frame = (const float*)d_in[2];
  const float* Wcls  = (const float*)d_in[3];
  const float* bcls  = (const float*)d_in[4];
  const float* Wdet  = (const float*)d_in[5];
  const float* Wr1   = (const float*)d_in[7];
  const float* br1   = (const float*)d_in[8];
  const float* Wr2   = (const float*)d_in[9];
  const float* br2   = (const float*)d_in[10];
  const float* ssb   = (const float*)d_in[11];
  const float* isw   = (const float*)d_in[12];
  const int*   label = (const int*)d_in[13];

  char* ws = (char*)d_ws;
  float*  S     = (float*)(ws + OFF_S);
  float*  scal  = (float*)(ws + OFF_SCAL);
  float*  dcs   = (float*)(ws + OFF_DCS);
  float*  b1    = (float*)(ws + OFF_B1);
  float*  b2    = (float*)(ws + OFF_B2);
  float*  lse1  = (float*)(ws + OFF_LSE1);
  float*  lse2  = (float*)(ws + OFF_LSE2);
  float*  clsp  = (float*)(ws + OFF_CLSP);
  float*  rp1   = (float*)(ws + OFF_RP1);
  ushort* Wp    = (ushort*)(ws + OFF_WP);
  float*  Spart = (float*)(ws + OFF_SPART);

  hipMemsetAsync(scal, 0, 16, stream);
  k_pack<<<1536, 256, 0, stream>>>(Wcls, Wr1, Wr2, Wdet, Wp);
  k_gemm<<<1024, 256, 0, stream>>>(roi, frame, ctx, Wp, Spart);
  k_rr<<<128, 256, 0, stream>>>(Spart, bcls, br1, br2, S, clsp, rp1, lse1, lse2);
  k_col<<<20, 256, 0, stream>>>(S, clsp, rp1, isw, ssb, bcls, dcs, b1, b2);
  k_sup<<<16, 256, 0, stream>>>(S, ssb, isw, label, b1, b2, lse1, lse2, br1, br2, scal);
  k_final<<<1, 64, 0, stream>>>(dcs, label, scal, (float*)d_out);
}

// Round 6
// 84.617 us; speedup vs baseline: 1.0721x; 1.0721x over previous
//
#include <hip/hip_runtime.h>

typedef __attribute__((ext_vector_type(4))) float f32x4;
typedef __attribute__((ext_vector_type(8))) short short8;
typedef __attribute__((ext_vector_type(4))) unsigned int u32x4;

#define N_ROWS 4096
#define KDIM   4096
#define NC     96     // [cls 0..19][r1 20..40][r2 41..61][pad][det 64..83][pad]
#define GSPLIT 4      // k splits (1024 k each)

__device__ inline short f2bf(float f) {
  unsigned u = __builtin_bit_cast(unsigned, f);
  u += 0x7FFFu + ((u >> 16) & 1u);   // RNE
  return (short)(u >> 16);
}

__device__ inline unsigned cvtpk(float lo, float hi) {
  unsigned r;
  asm("v_cvt_pk_bf16_f32 %0, %1, %2" : "=v"(r) : "v"(lo), "v"(hi));
  return r;
}

typedef const __attribute__((address_space(1))) void gas_t;
typedef __attribute__((address_space(3))) void las_t;
__device__ __forceinline__ void gll16(const float* g, void* l) {
  __builtin_amdgcn_global_load_lds((gas_t*)g, (las_t*)l, 16, 0, 0);
}

// ---------------- K0: pack weights into bf16 B-fragment order (R0-verified mapping) ----------------
// Wp flat index: ((K*6 + ct)*64 + l)*8 + j ; k = K*32 + (l>>4)*8 + j ; col = ct*16 + (l&15)
__global__ void k_pack(const float* __restrict__ Wcls, const float* __restrict__ Wr1,
                       const float* __restrict__ Wr2, const float* __restrict__ Wdet,
                       ushort* __restrict__ Wp) {
  int t = blockIdx.x * 256 + threadIdx.x;            // 0 .. 128*3072-1
  int K = t / 3072;
  int rem = t - K * 3072;
  int ct = rem >> 9;
  int rem2 = rem & 511;
  int l = rem2 >> 3;
  int j = rem2 & 7;
  int k = K * 32 + (l >> 4) * 8 + j;
  int col = ct * 16 + (l & 15);
  float v = 0.f;
  if (col < 20)                 v = Wcls[k * 20 + col];
  else if (col < 41)            v = Wr1[k * 21 + (col - 20)];
  else if (col < 62)            v = Wr2[k * 21 + (col - 41)];
  else if (col >= 64 && col < 84) v = Wdet[k * 20 + (col - 64)];
  Wp[t] = (ushort)f2bf(v);
}

// ---------------- K1: 1-wave blocks, global_load_lds A-stream, barrier-free ----------------
#define WAITV(N) asm volatile("s_waitcnt vmcnt(" #N ")" ::: "memory")
#define SB() __builtin_amdgcn_sched_barrier(0)
#define ABUF(P) ((P) == 0 ? bufA0 : (P) == 1 ? bufA1 : bufA2)

// stage A chunk C (64 k) for all 3 matrices into LDS buffer C%3 (12 global_load_lds)
#define STAGE_A(C) do {                                                       \
    char* _b = ABUF((C) % 3);                                                 \
    _Pragma("unroll") for (int m = 0; m < 3; ++m) {                           \
      const float* _s = (m == 0 ? pR : m == 1 ? pF : pX) + (size_t)(C) * 64;  \
      _Pragma("unroll") for (int i = 0; i < 4; ++i)                           \
        gll16(_s + (size_t)i * 4 * KDIM, _b + m * 4096 + i * 1024);           \
    }                                                                         \
  } while (0)

// load B chunk C (2 ksteps x 6 frags) into reg dbuf C&1 (12 dwordx4 loads, L2-resident)
#define STAGE_B(C) do {                                                       \
    _Pragma("unroll") for (int q = 0; q < 12; ++q)                            \
      Bv[(C) & 1][q] = *(const short8*)(pb + (size_t)(C) * 6144 +             \
                                        (q / 6) * 3072 + (q % 6) * 512);      \
  } while (0)

// swizzled LDS read of one 16B A-granule
#define LDA(P, M, KS, H)                                                      \
  (*(const f32x4*)(ABUF(P) + (M) * 4096 + base2 +                             \
                   ((((KS) * 8 + kg * 2 + (H)) ^ r3) << 4)))

#define COMPUTE(C) do {                                                       \
    _Pragma("unroll") for (int ks2 = 0; ks2 < 2; ++ks2) {                     \
      f32x4 r0 = LDA((C) % 3, 0, ks2, 0), r1 = LDA((C) % 3, 0, ks2, 1);       \
      f32x4 f0 = LDA((C) % 3, 1, ks2, 0), f1 = LDA((C) % 3, 1, ks2, 1);       \
      f32x4 x0 = LDA((C) % 3, 2, ks2, 0), x1 = LDA((C) % 3, 2, ks2, 1);       \
      u32x4 uR, uD;                                                           \
      uR.x = cvtpk(r0[0], r0[1]); uR.y = cvtpk(r0[2], r0[3]);                 \
      uR.z = cvtpk(r1[0], r1[1]); uR.w = cvtpk(r1[2], r1[3]);                 \
      uD.x = cvtpk(f0[0] - x0[0], f0[1] - x0[1]);                             \
      uD.y = cvtpk(f0[2] - x0[2], f0[3] - x0[3]);                             \
      uD.z = cvtpk(f1[0] - x1[0], f1[1] - x1[1]);                             \
      uD.w = cvtpk(f1[2] - x1[2], f1[3] - x1[3]);                             \
      const short8 aR = __builtin_bit_cast(short8, uR);                       \
      const short8 aD = __builtin_bit_cast(short8, uD);                       \
      _Pragma("unroll") for (int ct = 0; ct < 6; ++ct)                        \
        acc[ct] = __builtin_amdgcn_mfma_f32_16x16x32_bf16(                    \
            ct < 4 ? aR : aD, Bv[(C) & 1][ks2 * 6 + ct], acc[ct], 0, 0, 0);   \
    }                                                                         \
  } while (0)

#define CHUNK(C, NW) do {                                                     \
    if ((C) + 1 <= 15) { STAGE_B((C) + 1); SB(); }                            \
    if ((C) + 2 <= 15) { STAGE_A((C) + 2); SB(); }                            \
    WAITV(NW); SB();                                                          \
    COMPUTE(C);                                                               \
  } while (0)

__global__ __launch_bounds__(64, 1) void k_gemm(const float* __restrict__ roi,
    const float* __restrict__ frame, const float* __restrict__ ctx,
    const ushort* __restrict__ Wp, float* __restrict__ Spart) {
  __shared__ alignas(16) char bufA0[12288];
  __shared__ alignas(16) char bufA1[12288];
  __shared__ alignas(16) char bufA2[12288];
  const int l  = threadIdx.x;          // 0..63 (one wave per block)
  const int rt = blockIdx.x >> 2;      // 16-row tile 0..255
  const int g  = blockIdx.x & 3;       // k split (1024 floats)

  // stage-side: lane l covers row (i*4 + l>>4), 16B granule (l&15)^((l>>4)&3) [pre-swizzled src]
  const int rlhi = l >> 4;
  const int sw = (l & 15) ^ (rlhi & 3);
  const size_t srow = (size_t)(rt * 16 + rlhi) * KDIM + (size_t)g * 1024 + sw * 4;
  const float* pR = roi + srow;
  const float* pF = frame + srow;
  const float* pX = ctx + srow;
  const ushort* pb = Wp + (size_t)g * 32 * 3072 + l * 8;

  // read-side lane geometry (MFMA A-frag: row=lane&15, kgroup=lane>>4)
  const int rl = l & 15, kg = l >> 4, r3 = rl & 3;
  const unsigned base2 = (unsigned)((rl >> 2) * 1024 + r3 * 256);

  short8 Bv[2][12];
  f32x4 acc[6];
#pragma unroll
  for (int i = 0; i < 6; ++i) acc[i] = (f32x4){0.f, 0.f, 0.f, 0.f};

  // prologue (queue order: A0[12] B0[12] A1[12])
  STAGE_A(0); SB();
  STAGE_B(0); SB();
  STAGE_A(1); SB();

  // steady state: issue B(c+1), A(c+2); wait after-B(c) = A(c+1)+B(c+1)+A(c+2) = 36
  CHUNK(0, 36);  CHUNK(1, 36);  CHUNK(2, 36);  CHUNK(3, 36);
  CHUNK(4, 36);  CHUNK(5, 36);  CHUNK(6, 36);  CHUNK(7, 36);
  CHUNK(8, 36);  CHUNK(9, 36);  CHUNK(10, 36); CHUNK(11, 36);
  CHUNK(12, 36); CHUNK(13, 36); CHUNK(14, 24); CHUNK(15, 0);

  // epilogue: bounce C-tile through LDS (buf0 dead) for contiguous stores
  float* red = (float*)bufA0;
  const int rbase = (l >> 4) * 4;   // C/D: col=lane&15, row=(lane>>4)*4+reg [m89-verified]
  const int col = l & 15;
#pragma unroll
  for (int ct = 0; ct < 6; ++ct)
#pragma unroll
    for (int r = 0; r < 4; ++r)
      red[(rbase + r) * NC + ct * 16 + col] = acc[ct][r];
  asm volatile("s_waitcnt lgkmcnt(0)" ::: "memory"); SB();
  float* outp = Spart + (size_t)g * (N_ROWS * NC) + (size_t)rt * (16 * NC);
#pragma unroll
  for (int q = 0; q < 6; ++q) {
    f32x4 v = *(const f32x4*)(red + l * 24 + q * 4);
    *(f32x4*)(outp + l * 24 + q * 4) = v;
  }
}

// ---------------- K2: fused split-K reduce + per-row softmaxes ----------------
__global__ void k_rr(const float* __restrict__ Spart, const float* __restrict__ bcls,
    const float* __restrict__ br1, const float* __restrict__ br2,
    float* __restrict__ S, float* __restrict__ clsp, float* __restrict__ rp1,
    float* __restrict__ lse1, float* __restrict__ lse2) {
  const int b = blockIdx.x;            // 128 blocks x 32 rows
  const int t = threadIdx.x;
  const int base = b * 3072;
#pragma unroll
  for (int j = 0; j < 12; ++j) {
    const int e = base + j * 256 + t;
    float s = 0.f;
#pragma unroll
    for (int gg = 0; gg < GSPLIT; ++gg) s += Spart[(size_t)gg * (N_ROWS * NC) + e];
    S[e] = s;
  }
  __syncthreads();
  if (t < 32) {
    const int i = b * 32 + t;
    const float* sr = S + (size_t)i * NC;
    float s[21];
    float m = -3.4e38f;
    for (int c = 0; c < 20; ++c) { s[c] = sr[c] + bcls[c]; m = fmaxf(m, s[c]); }
    float sum = 0.f;
    for (int c = 0; c < 20; ++c) { float e = expf(s[c] - m); s[c] = e; sum += e; }
    float inv = 1.f / sum;
    for (int c = 0; c < 20; ++c) clsp[(size_t)i * 20 + c] = s[c] * inv;
    m = -3.4e38f;
    for (int c = 0; c < 21; ++c) { s[c] = sr[20 + c] + br1[c]; m = fmaxf(m, s[c]); }
    sum = 0.f;
    for (int c = 0; c < 21; ++c) { float e = expf(s[c] - m); s[c] = e; sum += e; }
    lse1[i] = m + logf(sum);
    inv = 1.f / sum;
    for (int c = 0; c < 21; ++c) rp1[(size_t)i * 21 + c] = s[c] * inv;
    m = -3.4e38f;
    for (int c = 0; c < 21; ++c) { s[c] = sr[41 + c] + br2[c]; m = fmaxf(m, s[c]); }
    sum = 0.f;
    for (int c = 0; c < 21; ++c) sum += expf(s[c] - m);
    lse2[i] = m + logf(sum);
  }
}

// ---------------- K3: per-column (det softmax stats, det_cls_score, argmaxes -> seed boxes) ----------------
__global__ __launch_bounds__(256) void k_col(const float* __restrict__ S,
    const float* __restrict__ clsp, const float* __restrict__ rp1,
    const float* __restrict__ isw, const float* __restrict__ ssb,
    const float* __restrict__ bcls,
    float* __restrict__ dcs, float* __restrict__ b1out, float* __restrict__ b2out) {
  const int c = blockIdx.x;
  const int t = threadIdx.x;
  __shared__ float rv[256];
  __shared__ int ri[256];
  float m = -3.4e38f;
  for (int i = t; i < N_ROWS; i += 256) m = fmaxf(m, S[(size_t)i * NC + 64 + c]);
  rv[t] = m; __syncthreads();
  for (int o = 128; o; o >>= 1) { if (t < o) rv[t] = fmaxf(rv[t], rv[t + o]); __syncthreads(); }
  const float M = rv[0]; __syncthreads();
  float se = 0.f, scd = 0.f, v1b = -3.4e38f, v2b = -3.4e38f;
  int i1 = 0, i2 = 0;
  for (int i = t; i < N_ROWS; i += 256) {
    float w = isw[i];
    float e = expf(S[(size_t)i * NC + 64 + c] - M);
    se += e;
    scd += (S[(size_t)i * NC + c] + bcls[c]) * e;
    float v1 = clsp[(size_t)i * 20 + c] * e * w;
    if (v1 > v1b) { v1b = v1; i1 = i; }
    float v2 = rp1[(size_t)i * 21 + c + 1] * w;
    if (v2 > v2b) { v2b = v2; i2 = i; }
  }
  rv[t] = se; __syncthreads();
  for (int o = 128; o; o >>= 1) { if (t < o) rv[t] += rv[t + o]; __syncthreads(); }
  const float SE = rv[0]; __syncthreads();
  rv[t] = scd; __syncthreads();
  for (int o = 128; o; o >>= 1) { if (t < o) rv[t] += rv[t + o]; __syncthreads(); }
  const float SCD = rv[0]; __syncthreads();
  rv[t] = v1b; ri[t] = i1; __syncthreads();
  for (int o = 128; o; o >>= 1) {
    if (t < o) { if (rv[t + o] > rv[t] || (rv[t + o] == rv[t] && ri[t + o] < ri[t])) { rv[t] = rv[t + o]; ri[t] = ri[t + o]; } }
    __syncthreads();
  }
  const int I1 = ri[0]; __syncthreads();
  rv[t] = v2b; ri[t] = i2; __syncthreads();
  for (int o = 128; o; o >>= 1) {
    if (t < o) { if (rv[t + o] > rv[t] || (rv[t + o] == rv[t] && ri[t + o] < ri[t])) { rv[t] = rv[t + o]; ri[t] = ri[t + o]; } }
    __syncthreads();
  }
  const int I2 = ri[0];
  if (t == 0) {
    dcs[c] = SCD / SE;
    for (int q = 0; q < 4; ++q) {
      b1out[c * 4 + q] = ssb[(size_t)I1 * 5 + 1 + q];
      b2out[c * 4 + q] = ssb[(size_t)I2 * 5 + 1 + q];
    }
  }
}

// ---------------- K4: per-row IoU supervision + refine-loss partials ----------------
__global__ __launch_bounds__(256) void k_sup(const float* __restrict__ S,
    const float* __restrict__ ssb, const float* __restrict__ isw,
    const int* __restrict__ label,
    const float* __restrict__ b1in, const float* __restrict__ b2in,
    const float* __restrict__ lse1, const float* __restrict__ lse2,
    const float* __restrict__ br1, const float* __restrict__ br2,
    float* __restrict__ scal) {
  __shared__ float q1[20][4], q2[20][4], a1[20], a2[20];
  __shared__ int pos[20];
  const int t = threadIdx.x;
  if (t < 20) {
    for (int q = 0; q < 4; ++q) { q1[t][q] = b1in[t * 4 + q]; q2[t][q] = b2in[t * 4 + q]; }
    a1[t] = (q1[t][2] - q1[t][0] + 1.f) * (q1[t][3] - q1[t][1] + 1.f);
    a2[t] = (q2[t][2] - q2[t][0] + 1.f) * (q2[t][3] - q2[t][1] + 1.f);
    pos[t] = (label[t] == 1);
  }
  __syncthreads();
  const int i = blockIdx.x * 256 + t;
  const float bx1 = ssb[(size_t)i * 5 + 1], by1 = ssb[(size_t)i * 5 + 2];
  const float bx2 = ssb[(size_t)i * 5 + 3], by2 = ssb[(size_t)i * 5 + 4];
  const float ab = (bx2 - bx1 + 1.f) * (by2 - by1 + 1.f);
  const float w = isw[i];
  float p1 = 0.f, n1 = 0.f, p2 = 0.f, n2 = 0.f;
  {
    float mo = -2.f; int gt = 0;
    for (int c = 0; c < 20; ++c) {
      float v = -1.f;
      if (pos[c]) {
        float xx1 = fmaxf(bx1, q1[c][0]), yy1 = fmaxf(by1, q1[c][1]);
        float xx2 = fminf(bx2, q1[c][2]), yy2 = fminf(by2, q1[c][3]);
        float iw = fmaxf(xx2 - xx1 + 1.f, 0.f), ih = fmaxf(yy2 - yy1 + 1.f, 0.f);
        float inter = iw * ih;
        v = inter / (ab + a1[c] - inter);
      }
      if (v > mo) { mo = v; gt = c; }
    }
    bool fg = mo > 0.5f;
    bool bg = (mo >= 0.1f) && (mo < 0.5f);
    if (fg || bg) {
      int col = fg ? gt + 1 : 0;
      float lp = S[(size_t)i * NC + 20 + col] + br1[col] - lse1[i];
      p1 = w * lp; n1 = 1.f;
    }
  }
  {
    float mo = -2.f; int gt = 0;
    for (int c = 0; c < 20; ++c) {
      float v = -1.f;
      if (pos[c]) {
        float xx1 = fmaxf(bx1, q2[c][0]), yy1 = fmaxf(by1, q2[c][1]);
        float xx2 = fminf(bx2, q2[c][2]), yy2 = fminf(by2, q2[c][3]);
        float iw = fmaxf(xx2 - xx1 + 1.f, 0.f), ih = fmaxf(yy2 - yy1 + 1.f, 0.f);
        float inter = iw * ih;
        v = inter / (ab + a2[c] - inter);
      }
      if (v > mo) { mo = v; gt = c; }
    }
    bool fg = mo > 0.5f;
    bool bg = (mo >= 0.1f) && (mo < 0.5f);
    if (fg || bg) {
      int col = fg ? gt + 1 : 0;
      float lp = S[(size_t)i * NC + 41 + col] + br2[col] - lse2[i];
      p2 = w * lp; n2 = 1.f;
    }
  }
  __shared__ float rs[256];
  float sums[4] = {p1, n1, p2, n2};
  float tot[4];
  for (int q = 0; q < 4; ++q) {
    rs[t] = sums[q]; __syncthreads();
    for (int o = 128; o; o >>= 1) { if (t < o) rs[t] += rs[t + o]; __syncthreads(); }
    tot[q] = rs[0]; __syncthreads();
  }
  if (t == 0) {
    atomicAdd(&scal[0], tot[0]); atomicAdd(&scal[1], tot[1]);
    atomicAdd(&scal[2], tot[2]); atomicAdd(&scal[3], tot[3]);
  }
}

// ---------------- K5: final scalar ----------------
__global__ void k_final(const float* __restrict__ dcs, const int* __restrict__ label,
                        const float* __restrict__ scal, float* __restrict__ out) {
  if (threadIdx.x == 0 && blockIdx.x == 0) {
    float cd = 0.f;
    for (int c = 0; c < 20; ++c) {
      float lab = (float)label[c];
      cd += fmaxf(1.f - lab * dcs[c], 0.f);
    }
    cd *= (1.f / 20.f);
    float rl1 = -scal[0] / scal[1];
    float rl2 = -scal[2] / scal[3];
    out[0] = cd + 0.1f * (rl1 + rl2);
  }
}

// ---------------- workspace layout (all 16B aligned) ----------------
constexpr size_t OFF_S     = 0;                               // 4096*96*4 = 1572864
constexpr size_t OFF_SCAL  = OFF_S + (size_t)N_ROWS * NC * 4; // 16
constexpr size_t OFF_DCS   = OFF_SCAL + 16;                   // 80
constexpr size_t OFF_B1    = OFF_DCS + 80;                    // 320
constexpr size_t OFF_B2    = OFF_B1 + 320;                    // 320
constexpr size_t OFF_LSE1  = OFF_B2 + 320;                    // 16384
constexpr size_t OFF_LSE2  = OFF_LSE1 + 16384;                // 16384
constexpr size_t OFF_CLSP  = OFF_LSE2 + 16384;                // 327680
constexpr size_t OFF_RP1   = OFF_CLSP + 327680;               // 344064
constexpr size_t OFF_WP    = OFF_RP1 + 344064;                // 786432
constexpr size_t OFF_SPART = OFF_WP + 786432;                 // 4*4096*96*4 = 6291456

extern "C" void kernel_launch(void* const* d_in, const int* in_sizes, int n_in,
                              void* d_out, int out_size, void* d_ws, size_t ws_size,
                              hipStream_t stream) {
  const float* roi   = (const float*)d_in[0];
  const float* ctx   = (const float*)d_in[1];
  const float* frame = (const float*)d_in[2];
  const float* Wcls  = (const float*)d_in[3];
  const float* bcls  = (const float*)d_in[4];
  const float* Wdet  = (const float*)d_in[5];
  const float* Wr1   = (const float*)d_in[7];
  const float* br1   = (const float*)d_in[8];
  const float* Wr2   = (const float*)d_in[9];
  const float* br2   = (const float*)d_in[10];
  const float* ssb   = (const float*)d_in[11];
  const float* isw   = (const float*)d_in[12];
  const int*   label = (const int*)d_in[13];

  char* ws = (char*)d_ws;
  float*  S     = (float*)(ws + OFF_S);
  float*  scal  = (float*)(ws + OFF_SCAL);
  float*  dcs   = (float*)(ws + OFF_DCS);
  float*  b1    = (float*)(ws + OFF_B1);
  float*  b2    = (float*)(ws + OFF_B2);
  float*  lse1  = (float*)(ws + OFF_LSE1);
  float*  lse2  = (float*)(ws + OFF_LSE2);
  float*  clsp  = (float*)(ws + OFF_CLSP);
  float*  rp1   = (float*)(ws + OFF_RP1);
  ushort* Wp    = (ushort*)(ws + OFF_WP);
  float*  Spart = (float*)(ws + OFF_SPART);

  hipMemsetAsync(scal, 0, 16, stream);
  k_pack<<<1536, 256, 0, stream>>>(Wcls, Wr1, Wr2, Wdet, Wp);
  k_gemm<<<1024, 64, 0, stream>>>(roi, frame, ctx, Wp, Spart);
  k_rr<<<128, 256, 0, stream>>>(Spart, bcls, br1, br2, S, clsp, rp1, lse1, lse2);
  k_col<<<20, 256, 0, stream>>>(S, clsp, rp1, isw, ssb, bcls, dcs, b1, b2);
  k_sup<<<16, 256, 0, stream>>>(S, ssb, isw, label, b1, b2, lse1, lse2, br1, br2, scal);
  k_final<<<1, 64, 0, stream>>>(dcs, label, scal, (float*)d_out);
}